// Round 15
// baseline (158.707 us; speedup 1.0000x reference)
//
#include <hip/hip_runtime.h>
#include <math.h>

#define BB 4
#define CC 256
#define DD 32
#define NN 4096

typedef __attribute__((ext_vector_type(8))) short short8;
typedef __attribute__((ext_vector_type(4))) float floatx4;
typedef __attribute__((ext_vector_type(16))) float floatx16;
typedef __attribute__((ext_vector_type(4))) int intx4;
typedef __attribute__((ext_vector_type(2))) int intx2;

#define SCALEF (0.17677669529663687f * 1.4426950408889634f)  // 1/sqrt(32)*log2(e)

// float -> bf16 round-to-nearest-even
__device__ __forceinline__ ushort f2bf(float f) {
    unsigned int u = __builtin_bit_cast(unsigned int, f);
    u += 0x7FFFu + ((u >> 16) & 1u);
    return (ushort)(u >> 16);
}
// pack two floats' bf16 truncations into one dword with a single v_perm_b32
__device__ __forceinline__ int pk_trunc(float a, float b) {
    return (int)__builtin_amdgcn_perm(__builtin_bit_cast(unsigned, b),
                                      __builtin_bit_cast(unsigned, a),
                                      0x07060302u);
}
__device__ __forceinline__ float fast_exp2(float x) {
#if __has_builtin(__builtin_amdgcn_exp2f)
    return __builtin_amdgcn_exp2f(x);
#else
    return exp2f(x);
#endif
}
// permlane32_swap: a'.hi <- b.lo, b'.lo <- a.hi (lo/hi = 32-lane halves)
__device__ __forceinline__ void plswap(int& a, int& b) {
#if __has_builtin(__builtin_amdgcn_permlane32_swap)
    intx2 r = __builtin_amdgcn_permlane32_swap(a, b, false, false);
    a = r[0]; b = r[1];
#else
    const int lane = threadIdx.x & 63;
    const bool hi = lane >= 32;
    int a2 = __shfl(a, lane ^ 32);
    int b2 = __shfl(b, lane ^ 32);
    int na = hi ? b2 : a;
    int nb = hi ? b : a2;
    a = na; b = nb;
#endif
}

// ---------------------------------------------------------------------------
// Kernel 1: FUSED transpose + QKV projection v3 — n-tile 64 -> 32 for 2x TLP.
// Grid (128 n-tiles, 4 b) = 512 blocks = 2/CU (R13 was 256 = 1/CU and, like
// every 1-block/CU kernel this session, latency-bound).  LDS 17 KB; staging
// one pass (512 thr x 4 c-rows x 4 n); per-wave GEMM 32o x 32n (acc[2][2]).
// All store layouts / index algebra verbatim (fn range 2 instead of 4), so
// attn_proj inputs are bit-identical.  [R14 resubmit: container failure,
// no kernel verdict — unchanged retry.]
// ---------------------------------------------------------------------------
#define QTP 264   // LDS pitch in ushorts (132 dwords; stride 4 banks -> <=2-way)
__global__ __launch_bounds__(640) void qkv_fused(
    const float* __restrict__ x,
    const float* __restrict__ Wq, const float* __restrict__ bq,
    const float* __restrict__ Wk, const float* __restrict__ bk,
    const float* __restrict__ Wv, const float* __restrict__ bv,
    const float* __restrict__ Wp, ushort* __restrict__ Wpb,
    ushort* __restrict__ qb, ushort* __restrict__ kb, ushort* __restrict__ vb)
{
    __shared__ ushort tile[32 * QTP];   // ~17 KB

    const int t = threadIdx.x;
    const int wave = t >> 6;                 // 0..9 = mt
    const int lane = t & 63;
    const int l15 = lane & 15, qd = lane >> 4;
    const int b = blockIdx.y;
    const int n0 = blockIdx.x * 32;
    const int mt = wave;

    // ---- (a) Wp -> Wpb frag-native conversion (first 64 blocks) ----
    const int bid = blockIdx.y * gridDim.x + blockIdx.x;
    if (bid < 64 && t < 256) {
        const int e = (bid * 256 + t) * 4;   // 64 blocks * 1024 = 256*256
        const int row = e >> 8, col = e & 255;
        const floatx4 w = *(const floatx4*)(Wp + (size_t)row * CC + col);
        int2 d;
        d.x = pk_trunc(w[0], w[1]);
        d.y = pk_trunc(w[2], w[3]);
        // Wpb frag-native: [col>>3][row][col&7]; col&7 in {0,4} -> int2 fits
        *(int2*)(Wpb + (size_t)(col >> 3) * (CC * 8) + row * 8 + (col & 7)) = d;
    }

    // ---- (b) stage x slice -> LDS bf16 [32n][256c], one pass, 512 thr ----
    if (t < 512) {
        const int cl = (t >> 3) * 4;   // 0..252, 4 c-rows per thread
        const int nl = (t & 7) * 4;    // 0..28, 4 n-cols per thread
        const float* src = x + ((size_t)b * CC + cl) * NN + n0 + nl;
        floatx4 v[4];
        #pragma unroll
        for (int i = 0; i < 4; ++i) v[i] = *(const floatx4*)(src + (size_t)i * NN);
        #pragma unroll
        for (int j = 0; j < 4; ++j) {
            *(int*)&tile[(nl + j) * QTP + cl]     = pk_trunc(v[0][j], v[1][j]);
            *(int*)&tile[(nl + j) * QTP + cl + 2] = pk_trunc(v[2][j], v[3][j]);
        }
    }
    __syncthreads();

    // ---- (c) per-wave GEMM: A = W rows (fp32, converted in-register) ----
    const float* wr[2];
    if (mt == 0) {
        wr[0] = Wq + (size_t)l15 * CC;
        wr[1] = Wq + (size_t)(16 + l15) * CC;
    } else if (mt == 1) {
        wr[0] = Wk + (size_t)l15 * CC;
        wr[1] = Wk + (size_t)(16 + l15) * CC;
    } else {
        wr[0] = Wv + (size_t)((mt - 2) * 32 + l15) * CC;
        wr[1] = Wv + (size_t)((mt - 2) * 32 + 16 + l15) * CC;
    }

    floatx4 z = {0.f, 0.f, 0.f, 0.f};
    floatx4 acc[2][2];   // [fm][fn]: 32 o x 32 n
    acc[0][0] = z; acc[0][1] = z; acc[1][0] = z; acc[1][1] = z;

    #pragma unroll
    for (int k0 = 0; k0 < CC; k0 += 32) {
        short8 af[2], bfr[2];
        #pragma unroll
        for (int f = 0; f < 2; ++f) {
            const float* p = wr[f] + k0 + qd * 8;
            float w[8];
            #pragma unroll
            for (int j = 0; j < 8; ++j) w[j] = p[j];
            if (mt == 0) {
                #pragma unroll
                for (int j = 0; j < 8; ++j) w[j] *= SCALEF;
            }
            intx4 d;
            d[0] = pk_trunc(w[0], w[1]); d[1] = pk_trunc(w[2], w[3]);
            d[2] = pk_trunc(w[4], w[5]); d[3] = pk_trunc(w[6], w[7]);
            af[f] = __builtin_bit_cast(short8, d);
            bfr[f] = *(const short8*)&tile[(f * 16 + l15) * QTP + k0 + qd * 8];
        }
        #pragma unroll
        for (int fm = 0; fm < 2; ++fm)
            #pragma unroll
            for (int fn = 0; fn < 2; ++fn)
                acc[fm][fn] = __builtin_amdgcn_mfma_f32_16x16x32_bf16(af[fm], bfr[fn], acc[fm][fn], 0, 0, 0);
    }

    // ---- store (verbatim layouts; fn range 2) ----
    #pragma unroll
    for (int fm = 0; fm < 2; ++fm) {
        const int o0 = fm * 16 + qd * 4;
        if (mt == 0) {
            const floatx4 bb = *(const floatx4*)(bq + o0);
            #pragma unroll
            for (int fn = 0; fn < 2; ++fn) {
                ushort4 h;
                h.x = f2bf(acc[fm][fn][0] + bb[0] * SCALEF);
                h.y = f2bf(acc[fm][fn][1] + bb[1] * SCALEF);
                h.z = f2bf(acc[fm][fn][2] + bb[2] * SCALEF);
                h.w = f2bf(acc[fm][fn][3] + bb[3] * SCALEF);
                *(ushort4*)(qb + ((size_t)b * NN + n0 + fn * 16 + l15) * DD + o0) = h;
            }
        } else if (mt == 1) {
            const floatx4 bb = *(const floatx4*)(bk + o0);
            #pragma unroll
            for (int fn = 0; fn < 2; ++fn) {
                ushort4 h;
                h.x = f2bf(acc[fm][fn][0] + bb[0]);
                h.y = f2bf(acc[fm][fn][1] + bb[1]);
                h.z = f2bf(acc[fm][fn][2] + bb[2]);
                h.w = f2bf(acc[fm][fn][3] + bb[3]);
                // kb frag layout: [(n>>4)][d>>3][n&15][d&7]
                *(ushort4*)(kb + (size_t)b * NN * DD
                                 + (size_t)(n0 / 16 + fn) * 512
                                 + (fm * 2 + (qd >> 1)) * 128
                                 + l15 * 8 + (qd & 1) * 4) = h;
            }
        } else {
            const int oc0 = (mt - 2) * 32 + o0;
            const floatx4 bb = *(const floatx4*)(bv + oc0);
            #pragma unroll
            for (int r = 0; r < 4; ++r)
                #pragma unroll
                for (int fn = 0; fn < 2; ++fn)
                    // vb frag layout: [(k>>4)][c][k&15]
                    vb[(size_t)b * CC * NN
                       + (size_t)(n0 / 16 + fn) * (CC * 16)
                       + (oc0 + r) * 16 + l15] = f2bf(acc[fm][fn][r] + bb[r]);
        }
    }
}

// ---------------------------------------------------------------------------
// Kernel 2: FUSED flash attention + output projection + residual
// (R13-VERBATIM).  Grid (8,32) = 256 blocks, 8 waves; wave (kh=w&3, ch=w>>2)
// runs the R12 attn main loop for c-half ch; kh-tree per ch; kh==0 waves
// write normalized ao to LDS frag-native; all 8 waves then proj GEMM + out.
// ---------------------------------------------------------------------------
__global__ __launch_bounds__(512, 2) void attn_proj(
    const ushort* __restrict__ qb, const ushort* __restrict__ kb,
    const ushort* __restrict__ vb, const ushort* __restrict__ Wpb,
    const float* __restrict__ bp, const float* __restrict__ x,
    const float* __restrict__ gamma, float* __restrict__ out)
{
    __shared__ float red[2][2][8192];   // [ch][slot][((qg*4+cg)*16 + r)*64 + lane]
    __shared__ float lred[2][2][64];    // [ch][slot][qg*32 + (lane&31)]
    ushort* ao_u = (ushort*)&red[0][0][0];   // 32 KB alias: ao[c>>3][n][c&7]

    const int t = threadIdx.x;
    const int w = t >> 6;                // wave 0..7
    const int kh = w & 3;                // key-quarter
    const int ch = w >> 2;               // c-half 0..1
    const int lane = t & 63;
    const int l31 = lane & 31;
    const bool hi = lane >= 32;
    const int hib = hi ? 8 : 0;
    const int slot = blockIdx.x;
    const int b = slot >> 1;
    const int qt = (slot & 1) * 32 + blockIdx.y;
    const int q0 = qt * 64;
    const int c0 = ch * 128;

    // Q B-frags: B[d][q], col=lane&31=q, k=d=hib+j
    short8 qf[2][2];
    #pragma unroll
    for (int qg = 0; qg < 2; ++qg)
        #pragma unroll
        for (int dh = 0; dh < 2; ++dh)
            qf[qg][dh] = *(const short8*)(qb + ((size_t)b * NN + q0 + qg * 32 + l31) * DD + dh * 16 + hib);

    // K frag-native: key = kh*1024 + kt*32 + l31, d = (frag)*16 + hib + j
    const ushort* krow = kb + (size_t)b * NN * DD + (size_t)kh * 64 * 512
                            + (l31 >> 4) * 512 + (l31 & 15) * 8 + hib * 16;  // hib*16 = hi*128
    // V frag-native: k = kh*1024 + kt*32 + k2*16 + hib + j, c = c0+cg*32+l31
    const ushort* vrow = vb + (size_t)b * CC * NN + (size_t)kh * 64 * (CC * 16)
                            + (c0 + l31) * 16 + hib;

    floatx16 z16 = {0.f,0.f,0.f,0.f,0.f,0.f,0.f,0.f,0.f,0.f,0.f,0.f,0.f,0.f,0.f,0.f};
    floatx16 acc[2][4];   // [qg][cg]: 64q x 128c wave tile
    #pragma unroll
    for (int qg = 0; qg < 2; ++qg)
        #pragma unroll
        for (int cg = 0; cg < 4; ++cg) acc[qg][cg] = z16;
    float lsum[2] = {0.f, 0.f};

    for (int kt = 0; kt < 32; ++kt) {
        short8 kf0 = *(const short8*)(krow);         // d 0..15
        short8 kf1 = *(const short8*)(krow + 256);   // d 16..31
        krow += 1024;                                // 2 key-blocks of 512
        short8 vf[4][2];
        #pragma unroll
        for (int cg = 0; cg < 4; ++cg)
            #pragma unroll
            for (int k2 = 0; k2 < 2; ++k2)
                vf[cg][k2] = *(const short8*)(vrow + cg * 512 + k2 * (CC * 16));
        vrow += 2 * (CC * 16);

        short8 ptB[2][2];   // [qg][k-half]: PV B-frags
        #pragma unroll
        for (int qg = 0; qg < 2; ++qg) {
            floatx16 s = __builtin_amdgcn_mfma_f32_32x32x16_bf16(kf0, qf[qg][0], z16, 0, 0, 0);
            s = __builtin_amdgcn_mfma_f32_32x32x16_bf16(kf1, qf[qg][1], s, 0, 0, 0);

            float e[16];
            #pragma unroll
            for (int r = 0; r < 16; ++r) e[r] = fast_exp2(s[r]);

            lsum[qg] += (((e[0]+e[1])+(e[2]+e[3]))+((e[4]+e[5])+(e[6]+e[7])))
                      + (((e[8]+e[9])+(e[10]+e[11]))+((e[12]+e[13])+(e[14]+e[15])));

            // keys 0-15 (B-frag k-half 0)
            int a0 = pk_trunc(e[0], e[1]),  b0 = pk_trunc(e[2], e[3]);
            int c0w = pk_trunc(e[4], e[5]), d0 = pk_trunc(e[6], e[7]);
            plswap(a0, c0w);
            plswap(b0, d0);
            intx4 f0 = {a0, b0, c0w, d0};
            ptB[qg][0] = __builtin_bit_cast(short8, f0);

            // keys 16-31 (B-frag k-half 1)
            int a1 = pk_trunc(e[8], e[9]),   b1 = pk_trunc(e[10], e[11]);
            int c1 = pk_trunc(e[12], e[13]), d1 = pk_trunc(e[14], e[15]);
            plswap(a1, c1);
            plswap(b1, d1);
            intx4 f1 = {a1, b1, c1, d1};
            ptB[qg][1] = __builtin_bit_cast(short8, f1);
        }

        __builtin_amdgcn_s_setprio(1);
        #pragma unroll
        for (int cg = 0; cg < 4; ++cg)
            #pragma unroll
            for (int qg = 0; qg < 2; ++qg) {
                acc[qg][cg] = __builtin_amdgcn_mfma_f32_32x32x16_bf16(vf[cg][0], ptB[qg][0], acc[qg][cg], 0, 0, 0);
                acc[qg][cg] = __builtin_amdgcn_mfma_f32_32x32x16_bf16(vf[cg][1], ptB[qg][1], acc[qg][cg], 0, 0, 0);
            }
        __builtin_amdgcn_s_setprio(0);
    }

    // fold partner-lane key-halves (each lane summed only its 16 of 32 keys)
    #pragma unroll
    for (int qg = 0; qg < 2; ++qg)
        lsum[qg] += __shfl(lsum[qg], lane ^ 32);

    // ---- reduction tree over key-quarters (within each ch) ----
    if (kh & 1) {
        const int s = kh >> 1;
        #pragma unroll
        for (int qg = 0; qg < 2; ++qg)
            #pragma unroll
            for (int cg = 0; cg < 4; ++cg)
                #pragma unroll
                for (int r = 0; r < 16; ++r)
                    red[ch][s][((qg * 4 + cg) * 16 + r) * 64 + lane] = acc[qg][cg][r];
        if (!hi)
            #pragma unroll
            for (int qg = 0; qg < 2; ++qg) lred[ch][s][qg * 32 + l31] = lsum[qg];
    }
    __syncthreads();
    if (!(kh & 1)) {
        const int s = kh >> 1;
        #pragma unroll
        for (int qg = 0; qg < 2; ++qg) {
            #pragma unroll
            for (int cg = 0; cg < 4; ++cg)
                #pragma unroll
                for (int r = 0; r < 16; ++r)
                    acc[qg][cg][r] += red[ch][s][((qg * 4 + cg) * 16 + r) * 64 + lane];
            lsum[qg] += lred[ch][s][qg * 32 + l31];
        }
    }
    __syncthreads();
    if (kh == 2) {
        #pragma unroll
        for (int qg = 0; qg < 2; ++qg)
            #pragma unroll
            for (int cg = 0; cg < 4; ++cg)
                #pragma unroll
                for (int r = 0; r < 16; ++r)
                    red[ch][0][((qg * 4 + cg) * 16 + r) * 64 + lane] = acc[qg][cg][r];
        if (!hi)
            #pragma unroll
            for (int qg = 0; qg < 2; ++qg) lred[ch][0][qg * 32 + l31] = lsum[qg];
    }
    __syncthreads();
    if (kh == 0) {
        #pragma unroll
        for (int qg = 0; qg < 2; ++qg) {
            #pragma unroll
            for (int cg = 0; cg < 4; ++cg)
                #pragma unroll
                for (int r = 0; r < 16; ++r)
                    acc[qg][cg][r] += red[ch][0][((qg * 4 + cg) * 16 + r) * 64 + lane];
            lsum[qg] += lred[ch][0][qg * 32 + l31];
        }
    }
    __syncthreads();   // all red reads done before ao alias is written

    // ---- kh==0 waves write normalized ao tile to LDS (frag-native) ----
    if (kh == 0) {
        #pragma unroll
        for (int qg = 0; qg < 2; ++qg) {
            const float inv = 1.0f / lsum[qg];
            const int nl = qg * 32 + l31;
            #pragma unroll
            for (int cg = 0; cg < 4; ++cg) {
                #pragma unroll
                for (int rq = 0; rq < 4; ++rq) {
                    ushort4 h;
                    h.x = f2bf(acc[qg][cg][rq * 4 + 0] * inv);
                    h.y = f2bf(acc[qg][cg][rq * 4 + 1] * inv);
                    h.z = f2bf(acc[qg][cg][rq * 4 + 2] * inv);
                    h.w = f2bf(acc[qg][cg][rq * 4 + 3] * inv);
                    *(ushort4*)&ao_u[(((ch * 16 + cg * 4 + rq) * 64) + nl) * 8 + (hi ? 4 : 0)] = h;
                }
            }
        }
    }
    __syncthreads();   // ao visible to all waves

    // ---- proj phase: wave w owns m-rows w*32..w*32+31, all 64 n ----
    const int m0w = w * 32;
    floatx16 pacc0 = z16, pacc1 = z16;
    #pragma unroll
    for (int kc = 0; kc < 16; ++kc) {
        const int cb = kc * 2 + (hi ? 1 : 0);
        short8 af  = *(const short8*)(Wpb + (size_t)cb * (CC * 8) + (m0w + l31) * 8);
        short8 bf0 = *(const short8*)&ao_u[(cb * 64 + l31) * 8];
        short8 bf1 = *(const short8*)&ao_u[(cb * 64 + 32 + l31) * 8];
        pacc0 = __builtin_amdgcn_mfma_f32_32x32x16_bf16(af, bf0, pacc0, 0, 0, 0);
        pacc1 = __builtin_amdgcn_mfma_f32_32x32x16_bf16(af, bf1, pacc1, 0, 0, 0);
    }
    const float g = gamma[0];
    #pragma unroll
    for (int r = 0; r < 16; ++r) {
        const int m = m0w + (r & 3) + 8 * (r >> 2) + (hi ? 4 : 0);
        const float bpv = bp[m];
        const size_t a0 = ((size_t)b * CC + m) * NN + q0 + l31;
        out[a0] = fmaf(g, pacc0[r] + bpv, x[a0]);
        const size_t a1 = a0 + 32;
        out[a1] = fmaf(g, pacc1[r] + bpv, x[a1]);
    }
}

extern "C" void kernel_launch(void* const* d_in, const int* in_sizes, int n_in,
                              void* d_out, int out_size, void* d_ws, size_t ws_size,
                              hipStream_t stream)
{
    const float* x     = (const float*)d_in[0];
    const float* Wq    = (const float*)d_in[1];
    const float* bq    = (const float*)d_in[2];
    const float* Wk    = (const float*)d_in[3];
    const float* bk    = (const float*)d_in[4];
    const float* Wv    = (const float*)d_in[5];
    const float* bv    = (const float*)d_in[6];
    const float* Wp    = (const float*)d_in[7];
    const float* bp    = (const float*)d_in[8];
    const float* gamma = (const float*)d_in[9];
    float* out = (float*)d_out;

    ushort* qbw = (ushort*)d_ws;                        // B*N*32  bf16 = 1 MB
    ushort* kbw = qbw + (size_t)BB * NN * DD;           // B*N*32  bf16 = 1 MB (frag layout)
    ushort* vbw = kbw + (size_t)BB * NN * DD;           // B*C*N   bf16 = 8 MB (frag layout)
    ushort* Wpb = vbw + (size_t)BB * CC * NN;           // 256*256 bf16 = 128 KB (frag layout)

    qkv_fused<<<dim3(NN / 32, BB), 640, 0, stream>>>(x, Wq, bq, Wk, bk, Wv, bv, Wp, Wpb, qbw, kbw, vbw);
    attn_proj<<<dim3(8, 32), 512, 0, stream>>>(qbw, kbw, vbw, Wpb, bp, x, gamma, out);
}